// Round 7
// baseline (78.910 us; speedup 1.0000x reference)
//
#include <hip/hip_runtime.h>
#include <hip/hip_bf16.h>
#include <math.h>

#define L_SEQ 1024
#define DIMSZ 512
#define NH 8
#define ND 64
#define NB 2
#define CHUNK 64
#define NC (L_SEQ / CHUNK)   // 16
#define BHTOT (NB * NH)      // 16
#define MTOT 2048
#define NTOT 1536
#define KEFF 512
#define BM 64
#define BN 96

typedef __attribute__((ext_vector_type(8))) _Float16 f16x8;
typedef __attribute__((ext_vector_type(4))) float f32x4;

__device__ static inline unsigned short f2h(float f) {
    union { _Float16 h; unsigned short u; } x;
    x.h = (_Float16)f;
    return x.u;
}

// ---------------------------------------------------------------------------
// GEMM (pack fused): C[2048 x 1536] = fp16(x) x fp16(Wcat)^T, K=512.
// Reg-staging: global fp32 -> VGPR -> cvt f16 -> swizzled ds_write_b128.
// 64x96 tile, BK=64, 4 waves (2x2, wave tile 32x48), grid 512 = 2 blocks/CU.
// Epilogue: bias + fp32 store to q/k/v.
// ---------------------------------------------------------------------------
__global__ __launch_bounds__(256) void gemm_kernel(
    const float* __restrict__ x,
    const float* __restrict__ wq, const float* __restrict__ wk, const float* __restrict__ wv,
    const float* __restrict__ bq, const float* __restrict__ bk, const float* __restrict__ bv,
    float* __restrict__ qo, float* __restrict__ ko, float* __restrict__ vo)
{
    __shared__ __align__(16) char lds[2][20480];   // [A 8KB | B 12KB] x 2
    const int tid  = threadIdx.x;
    const int lane = tid & 63;
    const int wave = tid >> 6;

    // XCD-aware swizzle: 512 blocks / 8 XCDs, M walks fastest within an XCD.
    const int bid = blockIdx.y * 32 + blockIdx.x;
    const int sw  = (bid & 7) * 64 + (bid >> 3);
    const int row0 = (sw >> 4) * BM;     // 32 M-tiles
    const int col0 = (sw & 15) * BN;     // 16 N-tiles
    const int wr = wave >> 1, wc = wave & 1;

    // --- staging task decomposition ---
    // A: 64 rows x 4 segs(16 floats) = 256 tasks (1/thread)
    // B: 96 rows x 4 segs = 384 tasks (thread tid does tid and tid+256<384)
    const int arow = tid >> 2, aseg = tid & 3;
    const int brow0 = tid >> 2, bseg0 = tid & 3;          // tasks 0..255
    const int t1 = tid + 256;
    const int brow1 = t1 >> 2, bseg1 = t1 & 3;            // tasks 256..383
    const bool hasB1 = (t1 < 384);

    const float* aptr = x + (size_t)(row0 + arow) * DIMSZ + aseg * 16;
    auto wrow = [&](int r) -> const float* {
        const int cabs = col0 + r;
        const int wh = cabs >> 9, cl = cabs & 511;
        const float* w = wh == 0 ? wq : (wh == 1 ? wk : wv);
        return w + (size_t)cl * DIMSZ;
    };
    const float* bptr0 = wrow(brow0) + bseg0 * 16;
    const float* bptr1 = hasB1 ? (wrow(brow1) + bseg1 * 16) : bptr0;

    // swizzled LDS byte destinations (two 16B quanta per 16-float segment)
    auto dsts = [](int row, int seg, int* d0, int* d1) {
        const int base = row * 128 + seg * 32;
        const int swz = (row & 7) << 4;
        *d0 = (base) ^ swz;
        *d1 = (base + 16) ^ swz;
    };
    int adst0, adst1, bdst00, bdst01, bdst10, bdst11;
    dsts(arow, aseg, &adst0, &adst1);
    dsts(brow0, bseg0, &bdst00, &bdst01);
    dsts(brow1, bseg1, &bdst10, &bdst11);

    float ar[16], br0[16], br1[16];
    auto load_regs = [&](int t) {
        const int k0 = t * 64;
        #pragma unroll
        for (int i = 0; i < 4; ++i) *(float4*)(ar + 4*i)  = ((const float4*)(aptr + k0))[i];
        #pragma unroll
        for (int i = 0; i < 4; ++i) *(float4*)(br0 + 4*i) = ((const float4*)(bptr0 + k0))[i];
        if (hasB1) {
            #pragma unroll
            for (int i = 0; i < 4; ++i) *(float4*)(br1 + 4*i) = ((const float4*)(bptr1 + k0))[i];
        }
    };
    auto cvt16 = [](const float* f, unsigned int* w) {
        #pragma unroll
        for (int i = 0; i < 8; ++i)
            w[i] = (unsigned)f2h(f[2*i]) | ((unsigned)f2h(f[2*i+1]) << 16);
    };
    auto write_lds = [&](int buf) {
        char* la = &lds[buf][0];
        char* lb = &lds[buf][8192];
        unsigned int w[8];
        cvt16(ar, w);
        *(uint4*)(la + adst0) = make_uint4(w[0], w[1], w[2], w[3]);
        *(uint4*)(la + adst1) = make_uint4(w[4], w[5], w[6], w[7]);
        cvt16(br0, w);
        *(uint4*)(lb + bdst00) = make_uint4(w[0], w[1], w[2], w[3]);
        *(uint4*)(lb + bdst01) = make_uint4(w[4], w[5], w[6], w[7]);
        if (hasB1) {
            cvt16(br1, w);
            *(uint4*)(lb + bdst10) = make_uint4(w[0], w[1], w[2], w[3]);
            *(uint4*)(lb + bdst11) = make_uint4(w[4], w[5], w[6], w[7]);
        }
    };

    f32x4 acc[2][3];
    const f32x4 zf = {0.f, 0.f, 0.f, 0.f};
    #pragma unroll
    for (int m = 0; m < 2; ++m)
        #pragma unroll
        for (int n = 0; n < 3; ++n) acc[m][n] = zf;

    const int rl = lane & 15;
    const int kg = lane >> 4;
    const int rswz = (rl & 7) << 4;

    auto compute = [&](int buf) {
        const char* la = &lds[buf][0];
        const char* lb = &lds[buf][8192];
        #pragma unroll
        for (int ks = 0; ks < 2; ++ks) {
            f16x8 av[2], bvv[3];
            #pragma unroll
            for (int m = 0; m < 2; ++m) {
                const int row = wr * 32 + m * 16 + rl;
                const int addr = (row * 128 + ks * 64 + kg * 16) ^ rswz;
                av[m] = *(const f16x8*)(la + addr);
            }
            #pragma unroll
            for (int n = 0; n < 3; ++n) {
                const int row = wc * 48 + n * 16 + rl;
                const int addr = (row * 128 + ks * 64 + kg * 16) ^ rswz;
                bvv[n] = *(const f16x8*)(lb + addr);
            }
            #pragma unroll
            for (int m = 0; m < 2; ++m)
                #pragma unroll
                for (int n = 0; n < 3; ++n)
                    acc[m][n] = __builtin_amdgcn_mfma_f32_16x16x32_f16(
                        av[m], bvv[n], acc[m][n], 0, 0, 0);
        }
    };

    load_regs(0);
    write_lds(0);
    __syncthreads();
    const int NT = KEFF / 64;   // 8
    for (int t = 0; t < NT; ++t) {
        if (t + 1 < NT) load_regs(t + 1);       // loads fly during compute
        compute(t & 1);
        if (t + 1 < NT) write_lds((t + 1) & 1); // other buffer; vmcnt implicit
        __syncthreads();
    }

    // --- epilogue: bias + fp32 store (16-col frag never straddles 512) ---
    #pragma unroll
    for (int n = 0; n < 3; ++n) {
        const int cabs = col0 + wc * 48 + n * 16 + rl;
        const int which = cabs >> 9;
        const int cl = cabs & 511;
        const float* bias = which == 0 ? bq : (which == 1 ? bk : bv);
        float* outp = which == 0 ? qo : (which == 1 ? ko : vo);
        const float bs = bias[cl];
        #pragma unroll
        for (int m = 0; m < 2; ++m) {
            const int rb = row0 + wr * 32 + m * 16 + kg * 4;
            #pragma unroll
            for (int r = 0; r < 4; ++r)
                outp[(size_t)(rb + r) * DIMSZ + cl] = acc[m][n][r] + bs;
        }
    }
}

// ---------------------------------------------------------------------------
// chunk_kv: KV_c[d,e] = sum_j lambda_d^{63-j} k[j,d] v[j,e].  Theta inline.
// ---------------------------------------------------------------------------
__global__ __launch_bounds__(256) void chunk_kv_kernel(
    const float* __restrict__ k, const float* __restrict__ v,
    const float* __restrict__ ph_re, const float* __restrict__ ph_im,
    const float* __restrict__ amplitude, float2* __restrict__ kv)
{
    const int bhc = blockIdx.x;
    const int c  = bhc & (NC - 1);
    const int bh = bhc >> 4;
    const int b = bh >> 3, h = bh & 7;
    const int tid = threadIdx.x;
    const int lane = tid & 63, grp = tid >> 6;

    __shared__ float ktr[CHUNK][ND + 1];
    __shared__ float kti[CHUNK][ND + 1];
    __shared__ float vs[CHUNK][ND + 1];

    const float th = atan2f(ph_im[h*ND + lane], ph_re[h*ND + lane]);
    const float la = -logf(1.0f + expf(-amplitude[h]));   // log(sigmoid(a))

    for (int jj = 0; jj < 16; ++jj) {
        const int j = grp*16 + jj;
        const int l = c*CHUNK + j;
        const size_t off = ((size_t)(b*L_SEQ + l)) * DIMSZ + h*ND + lane;
        const float kk = k[off];
        const float vv = v[off];
        const float p = (float)(CHUNK - 1 - j);
        const float ap = expf(la * p);
        float s, ct; sincosf(th * p, &s, &ct);
        ktr[j][lane] = kk * ap * ct;
        kti[j][lane] = kk * ap * s;
        vs[j][lane]  = vv;
    }
    __syncthreads();

    float accr[16], acci[16];
    #pragma unroll
    for (int dd = 0; dd < 16; ++dd) { accr[dd] = 0.f; acci[dd] = 0.f; }
    for (int j = 0; j < CHUNK; ++j) {
        const float vv = vs[j][lane];
        #pragma unroll
        for (int dd = 0; dd < 16; ++dd) {
            const int d = grp*16 + dd;
            accr[dd] = fmaf(ktr[j][d], vv, accr[dd]);
            acci[dd] = fmaf(kti[j][d], vv, acci[dd]);
        }
    }
    float2* dst = kv + (size_t)bhc * (ND*ND);
    #pragma unroll
    for (int dd = 0; dd < 16; ++dd) {
        const int d = grp*16 + dd;
        dst[d*ND + lane] = make_float2(accr[dd], acci[dd]);
    }
}

// ---------------------------------------------------------------------------
// scan: B_{c+1} = lambda^64 * B_c + KV_c (complex), B_0 = last_conv.
// kvB[bhc] := state BEFORE chunk c.  Theta inline; loads prefetched.
// ---------------------------------------------------------------------------
__global__ __launch_bounds__(256) void scan_kernel(
    float2* __restrict__ kvB,
    const float* __restrict__ lc_re, const float* __restrict__ lc_im,
    const float* __restrict__ ph_re, const float* __restrict__ ph_im,
    const float* __restrict__ amplitude)
{
    const int gid = blockIdx.x * 256 + threadIdx.x;   // 65536
    const int bh = gid >> 12;
    const int idx = gid & 4095;
    const int h = bh & 7;
    const int d = idx >> 6;

    const float th = atan2f(ph_im[h*ND + d], ph_re[h*ND + d]);
    const float la = -logf(1.0f + expf(-amplitude[h]));
    const float ampC = expf(la * (float)CHUNK);
    float s, ct; sincosf(th * (float)CHUNK, &s, &ct);
    const float aCr = ampC * ct, aCi = ampC * s;

    float2* base = kvB + (size_t)bh * NC * (ND*ND) + idx;
    float2 t[NC];
    #pragma unroll
    for (int c = 0; c < NC; ++c) t[c] = base[(size_t)c * (ND*ND)];

    float Sr = lc_re[h*ND*ND + idx];
    float Si = lc_im[h*ND*ND + idx];
    #pragma unroll
    for (int c = 0; c < NC; ++c) {
        base[(size_t)c * (ND*ND)] = make_float2(Sr, Si);
        const float nr = aCr*Sr - aCi*Si + t[c].x;
        const float ni = aCr*Si + aCi*Sr + t[c].y;
        Sr = nr; Si = ni;
    }
}

// ---------------------------------------------------------------------------
// chunk_out: 512 blocks (bhc*2+half), 32 output rows each; asymmetric K/V
// loads; theta inline; B-tile reg prefetch -> LDS reuse for cross term.
// ---------------------------------------------------------------------------
__global__ __launch_bounds__(256) void chunk_out_kernel(
    const float* __restrict__ q, const float* __restrict__ k, const float* __restrict__ v,
    const float2* __restrict__ Bst,
    const float* __restrict__ ph_re, const float* __restrict__ ph_im,
    const float* __restrict__ amplitude, float* __restrict__ out)
{
    const int half = blockIdx.x & 1;
    const int bhc = blockIdx.x >> 1;
    const int c  = bhc & (NC - 1);
    const int bh = bhc >> 4;
    const int b = bh >> 3, h = bh & 7;
    const int tid = threadIdx.x;
    const int lane = tid & 63, grp = tid >> 6;
    const int ty = tid >> 4, tx = tid & 15;   // 2 rows x 4 cols per thread

    __shared__ float QR[32][ND + 1];
    __shared__ float QI[32][ND + 1];
    __shared__ float KR[CHUNK][ND + 1];   // rows 0..31 reused for SA
    __shared__ float KI[CHUNK][ND + 1];   // later reused for BR
    __shared__ float VS[CHUNK][ND + 1];   // later reused for BI
    __shared__ float cth[ND], sth[ND];

    const float la = -logf(1.0f + expf(-amplitude[h]));
    const int kmax = 32 + half * 32;      // rows of K/V this block needs

    // early B-tile loads into registers (latency hidden under scores/PV)
    float2 breg[16];
    const float2* Bbase = Bst + (size_t)bhc * (ND*ND);
    #pragma unroll
    for (int ii = 0; ii < 16; ++ii) breg[ii] = Bbase[tid * 16 + ii];

    const float th = atan2f(ph_im[h*ND + lane], ph_re[h*ND + lane]);
    if (tid < ND) { float s0, c0; sincosf(th, &s0, &c0); cth[tid] = c0; sth[tid] = s0; }
    #pragma unroll
    for (int jj = 0; jj < 8; ++jj) {
        const int jl = grp*8 + jj;
        const int jabs = half*32 + jl;
        const size_t off = ((size_t)(b*L_SEQ + c*CHUNK + jabs)) * DIMSZ + h*ND + lane;
        const float qq = q[off];
        float s, cc; sincosf(th * (float)jabs, &s, &cc);
        QR[jl][lane] = qq * cc; QI[jl][lane] = qq * s;
    }
    const int rpg = kmax >> 2;   // 8 or 16 rows per 64-lane group
    for (int jj = 0; jj < rpg; ++jj) {
        const int j = grp*rpg + jj;
        const size_t off = ((size_t)(b*L_SEQ + c*CHUNK + j)) * DIMSZ + h*ND + lane;
        const float kk = k[off], vv = v[off];
        float s, cc; sincosf(th * (float)j, &s, &cc);
        KR[j][lane] = kk * cc; KI[j][lane] = kk * s;
        VS[j][lane] = vv;
    }
    __syncthreads();

    // ---- intra scores A[jl, jp] = qr*kr + qi*ki ----
    // (half 0: jp >= 32 reads stale LDS; discarded by delta<0 below.)
    float accA[2][4] = {};
    for (int d = 0; d < ND; ++d) {
        float qrv[2], qiv[2], krv[4], kiv[4];
        #pragma unroll
        for (int i = 0; i < 2; ++i) { qrv[i] = QR[ty*2+i][d]; qiv[i] = QI[ty*2+i][d]; }
        #pragma unroll
        for (int u = 0; u < 4; ++u) { krv[u] = KR[tx*4+u][d]; kiv[u] = KI[tx*4+u][d]; }
        #pragma unroll
        for (int i = 0; i < 2; ++i)
            #pragma unroll
            for (int u = 0; u < 4; ++u)
                accA[i][u] = fmaf(qrv[i], krv[u], fmaf(qiv[i], kiv[u], accA[i][u]));
    }
    __syncthreads();

    float (*SA)[ND + 1] = KR;   // rows 0..31
    #pragma unroll
    for (int i = 0; i < 2; ++i) {
        const int jl = ty*2 + i;
        const int jabs = half*32 + jl;
        #pragma unroll
        for (int u = 0; u < 4; ++u) {
            const int jp = tx*4 + u;
            const int delta = jabs - jp;
            SA[jl][jp] = (delta >= 0) ? accA[i][u] * expf(la * (float)delta) : 0.0f;
        }
    }
    __syncthreads();

    // ---- PV ----
    float accO[2][4] = {};
    for (int jp = 0; jp < kmax; ++jp) {
        float av[2], vv[4];
        #pragma unroll
        for (int i = 0; i < 2; ++i) av[i] = SA[ty*2+i][jp];
        #pragma unroll
        for (int u = 0; u < 4; ++u) vv[u] = VS[jp][tx*4+u];
        #pragma unroll
        for (int i = 0; i < 2; ++i)
            #pragma unroll
            for (int u = 0; u < 4; ++u)
                accO[i][u] = fmaf(av[i], vv[u], accO[i][u]);
    }
    __syncthreads();

    // ---- stage B into LDS: BR -> KI, BI -> VS ----
    #pragma unroll
    for (int ii = 0; ii < 16; ++ii) {
        const int id2 = tid * 16 + ii;
        const int d = id2 >> 6, e = id2 & 63;
        KI[d][e] = breg[ii].x;
        VS[d][e] = breg[ii].y;
    }
    __syncthreads();

    // ---- cross: accC = Re( (q^ * e^{i theta}) . B ) ----
    float accC[2][4] = {};
    for (int d = 0; d < ND; ++d) {
        const float cd = cth[d], sd = sth[d];
        float brv[4], biv[4];
        #pragma unroll
        for (int u = 0; u < 4; ++u) { brv[u] = KI[d][tx*4+u]; biv[u] = VS[d][tx*4+u]; }
        #pragma unroll
        for (int i = 0; i < 2; ++i) {
            const float qr = QR[ty*2+i][d], qi = QI[ty*2+i][d];
            const float qcr = qr*cd - qi*sd;
            const float qci = qr*sd + qi*cd;
            #pragma unroll
            for (int u = 0; u < 4; ++u)
                accC[i][u] = fmaf(qcr, brv[u], fmaf(-qci, biv[u], accC[i][u]));
        }
    }

    #pragma unroll
    for (int i = 0; i < 2; ++i) {
        const int jabs = half*32 + ty*2 + i;
        const float cs = expf(la * (float)(jabs + 1));   // amp^{j+1}
        const size_t off = ((size_t)(b*L_SEQ + c*CHUNK + jabs)) * DIMSZ + h*ND + tx*4;
        *(float4*)(out + off) = make_float4(
            fmaf(cs, accC[i][0], accO[i][0]), fmaf(cs, accC[i][1], accO[i][1]),
            fmaf(cs, accC[i][2], accO[i][2]), fmaf(cs, accC[i][3], accO[i][3]));
    }
}

// ---------------------------------------------------------------------------
extern "C" void kernel_launch(void* const* d_in, const int* in_sizes, int n_in,
                              void* d_out, int out_size, void* d_ws, size_t ws_size,
                              hipStream_t stream)
{
    const float* x     = (const float*)d_in[0];
    const float* wq_w  = (const float*)d_in[1];
    const float* wq_b  = (const float*)d_in[2];
    const float* wk_w  = (const float*)d_in[3];
    const float* wk_b  = (const float*)d_in[4];
    const float* wv_w  = (const float*)d_in[5];
    const float* wv_b  = (const float*)d_in[6];
    const float* ph_re = (const float*)d_in[7];
    const float* ph_im = (const float*)d_in[8];
    const float* ampl  = (const float*)d_in[9];
    const float* lc_re = (const float*)d_in[10];
    const float* lc_im = (const float*)d_in[11];
    float* out = (float*)d_out;

    char* wsb = (char*)d_ws;
    const size_t MB = 1024 * 1024;
    float* q    = (float*)(wsb + 0);           // 4 MB
    float* k    = (float*)(wsb + 4 * MB);      // 4 MB
    float* v    = (float*)(wsb + 8 * MB);      // 4 MB
    float2* kvB = (float2*)(wsb + 12 * MB);    // 8 MB

    gemm_kernel<<<dim3(MTOT / BM, NTOT / BN), 256, 0, stream>>>(
        x, wq_w, wk_w, wv_w, wq_b, wk_b, wv_b, q, k, v);
    chunk_kv_kernel<<<BHTOT * NC, 256, 0, stream>>>(k, v, ph_re, ph_im, ampl, kvB);
    scan_kernel<<<(BHTOT * ND * ND) / 256, 256, 0, stream>>>(kvB, lc_re, lc_im, ph_re, ph_im, ampl);
    chunk_out_kernel<<<BHTOT * NC * 2, 256, 0, stream>>>(q, k, v, kvB, ph_re, ph_im, ampl, out);
}

// Round 9
// 42.456 us; speedup vs baseline: 1.8586x; 1.8586x over previous
//
#include <hip/hip_runtime.h>
#include <hip/hip_bf16.h>
#include <math.h>

#define L_SEQ 1024
#define DIMSZ 512
#define NH 8
#define ND 64
#define NB 2
#define CHUNK 64
#define NC (L_SEQ / CHUNK)   // 16
#define BHTOT (NB * NH)      // 16
#define MTOT 2048
#define NTOT 1536
#define KEFF 512
#define BM 64
#define BN 96

typedef __attribute__((ext_vector_type(8))) _Float16 f16x8;
typedef __attribute__((ext_vector_type(4))) float f32x4;

#define GLD16(g, l) __builtin_amdgcn_global_load_lds( \
    (const __attribute__((address_space(1))) unsigned int*)(g), \
    (__attribute__((address_space(3))) unsigned int*)(l), 16, 0, 0)

__device__ static inline unsigned short f2h(float f) {
    union { _Float16 h; unsigned short u; } x;
    x.h = (_Float16)f;
    return x.u;
}

// ---------------------------------------------------------------------------
// pack: [0,1024)   A[n][k] = fp16(x)            (2048 x 512)
//       [1024,1792) B[which*512+o][k] = fp16(W)  (1536 x 512)
// ---------------------------------------------------------------------------
__global__ __launch_bounds__(256) void pack_kernel(
    const float* __restrict__ x,
    const float* __restrict__ wq, const float* __restrict__ wk, const float* __restrict__ wv,
    unsigned short* __restrict__ A, unsigned short* __restrict__ Bm)
{
    const int bid = blockIdx.x;
    const int tid = threadIdx.x;
    if (bid < 1024) {
        const int i = bid * 256 + tid;
        const int n  = i >> 7;
        const int kq = (i & 127) << 2;
        const float4 xv = *(const float4*)(x + (size_t)n * DIMSZ + kq);
        *(ushort4*)(A + (size_t)n * KEFF + kq) =
            make_ushort4(f2h(xv.x), f2h(xv.y), f2h(xv.z), f2h(xv.w));
    } else {
        const int idx = bid - 1024;
        const int which = idx >> 8;
        const float* w = which == 0 ? wq : (which == 1 ? wk : wv);
        const int i = (idx & 255) * 256 + tid;
        const int o  = i >> 7;
        const int kq = (i & 127) << 2;
        const float4 wv4 = *(const float4*)(w + (size_t)o * DIMSZ + kq);
        *(ushort4*)(Bm + (size_t)(which * 512 + o) * KEFF + kq) =
            make_ushort4(f2h(wv4.x), f2h(wv4.y), f2h(wv4.z), f2h(wv4.w));
    }
}

// ---------------------------------------------------------------------------
// GEMM (R6, known-good): C[2048x1536] = A x B^T, MFMA 16x16x32 f16, K=512.
// ---------------------------------------------------------------------------
__global__ __launch_bounds__(256) void gemm_kernel(
    const unsigned short* __restrict__ A, const unsigned short* __restrict__ Bm,
    const float* __restrict__ bq, const float* __restrict__ bk, const float* __restrict__ bv,
    float* __restrict__ qo, float* __restrict__ ko, float* __restrict__ vo)
{
    __shared__ __align__(16) char lds[2][20480];   // [A 8KB | B 12KB] x 2
    const int tid  = threadIdx.x;
    const int lane = tid & 63;
    const int wave = tid >> 6;

    const int bid = blockIdx.y * 32 + blockIdx.x;
    const int sw  = (bid & 7) * 64 + (bid >> 3);
    const int row0 = (sw >> 4) * BM;
    const int col0 = (sw & 15) * BN;
    const int wr = wave >> 1, wc = wave & 1;

    const int srow = tid >> 3;
    const int sin  = (tid & 7) << 4;
    size_t goffA[2], goffB[3];
    #pragma unroll
    for (int c = 0; c < 2; ++c) {
        const int row = c * 32 + srow;
        const int swz = sin ^ ((row & 7) << 4);
        goffA[c] = (size_t)(row0 + row) * (KEFF * 2) + swz;
    }
    #pragma unroll
    for (int c = 0; c < 3; ++c) {
        const int row = c * 32 + srow;
        const int swz = sin ^ ((row & 7) << 4);
        goffB[c] = (size_t)(col0 + row) * (KEFF * 2) + swz;
    }
    const int ldst = tid * 16;
    const char* Abyte = (const char*)A;
    const char* Bbyte = (const char*)Bm;

    f32x4 acc[2][3];
    const f32x4 zf = {0.f, 0.f, 0.f, 0.f};
    #pragma unroll
    for (int m = 0; m < 2; ++m)
        #pragma unroll
        for (int n = 0; n < 3; ++n) acc[m][n] = zf;

    auto stage = [&](int buf, int t) {
        char* la = &lds[buf][0];
        char* lb = &lds[buf][8192];
        const size_t kb = (size_t)t * 128;
        #pragma unroll
        for (int c = 0; c < 2; ++c)
            GLD16(Abyte + goffA[c] + kb, la + c * 4096 + ldst);
        #pragma unroll
        for (int c = 0; c < 3; ++c)
            GLD16(Bbyte + goffB[c] + kb, lb + c * 4096 + ldst);
    };

    const int rl = lane & 15;
    const int kg = lane >> 4;
    const int rswz = (rl & 7) << 4;

    auto compute = [&](int buf) {
        const char* la = &lds[buf][0];
        const char* lb = &lds[buf][8192];
        #pragma unroll
        for (int ks = 0; ks < 2; ++ks) {
            f16x8 av[2], bvv[3];
            #pragma unroll
            for (int m = 0; m < 2; ++m) {
                const int row = wr * 32 + m * 16 + rl;
                const int addr = (row * 128 + ks * 64 + kg * 16) ^ rswz;
                av[m] = *(const f16x8*)(la + addr);
            }
            #pragma unroll
            for (int n = 0; n < 3; ++n) {
                const int row = wc * 48 + n * 16 + rl;
                const int addr = (row * 128 + ks * 64 + kg * 16) ^ rswz;
                bvv[n] = *(const f16x8*)(lb + addr);
            }
            #pragma unroll
            for (int m = 0; m < 2; ++m)
                #pragma unroll
                for (int n = 0; n < 3; ++n)
                    acc[m][n] = __builtin_amdgcn_mfma_f32_16x16x32_f16(
                        av[m], bvv[n], acc[m][n], 0, 0, 0);
        }
    };

    stage(0, 0);
    __syncthreads();
    const int NT = KEFF / 64;   // 8
    for (int t = 0; t < NT; ++t) {
        if (t + 1 < NT) stage((t + 1) & 1, t + 1);
        compute(t & 1);
        __syncthreads();
    }

    #pragma unroll
    for (int n = 0; n < 3; ++n) {
        const int cabs = col0 + wc * 48 + n * 16 + rl;
        const int which = cabs >> 9;
        const int cl = cabs & 511;
        const float* bias = which == 0 ? bq : (which == 1 ? bk : bv);
        float* outp = which == 0 ? qo : (which == 1 ? ko : vo);
        const float bs = bias[cl];
        #pragma unroll
        for (int m = 0; m < 2; ++m) {
            const int rb = row0 + wr * 32 + m * 16 + kg * 4;
            #pragma unroll
            for (int r = 0; r < 4; ++r)
                outp[(size_t)(rb + r) * DIMSZ + cl] = acc[m][n][r] + bs;
        }
    }
}

// ---------------------------------------------------------------------------
// chunk_kv (MFMA): KV^T[e][d] = sum_j (v[j,e] amp^{63-j}) * khat[j,d]
// khat[j,d] = k[j,d] * e^{i theta_d (63-j)}   (rotation in K, decay in V)
// LDS: KTR/KTI [d][j], VWT [e][j]  (dual row-major -> A/B frags).
// Output kvB[bhc] stored TRANSPOSED [e][d] (float2).
// ---------------------------------------------------------------------------
__global__ __launch_bounds__(256) void chunk_kv_kernel(
    const float* __restrict__ k, const float* __restrict__ v,
    const float* __restrict__ ph_re, const float* __restrict__ ph_im,
    const float* __restrict__ ampl, float2* __restrict__ kvB)
{
    __shared__ __align__(16) _Float16 KTR[64][72];
    __shared__ __align__(16) _Float16 KTI[64][72];
    __shared__ __align__(16) _Float16 VWT[64][72];

    const int bhc = blockIdx.x;
    const int c  = bhc & (NC - 1);
    const int bh = bhc >> 4;
    const int b = bh >> 3, h = bh & 7;
    const int tid = threadIdx.x;
    const int lane = tid & 63, w = tid >> 6;
    const int rl = lane & 15, kg = lane >> 4;

    const float la = -logf(1.0f + expf(-ampl[h]));
    const float th = atan2f(ph_im[h*ND + lane], ph_re[h*ND + lane]);

    #pragma unroll
    for (int jj = 0; jj < 16; ++jj) {
        const int j = w*16 + jj;
        const size_t off = ((size_t)(b*L_SEQ + c*CHUNK + j)) * DIMSZ + h*ND + lane;
        const float kk = k[off], vv = v[off];
        const float p = (float)(CHUNK - 1 - j);
        const float ap = expf(la * p);
        float s, ct; sincosf(th * p, &s, &ct);
        KTR[lane][j] = (_Float16)(kk * ct);
        KTI[lane][j] = (_Float16)(kk * s);
        VWT[lane][j] = (_Float16)(vv * ap);
    }
    __syncthreads();

    float2* dst = kvB + (size_t)bhc * (ND*ND);
    const f32x4 zf = {0.f, 0.f, 0.f, 0.f};
    #pragma unroll
    for (int i = 0; i < 4; ++i) {
        const int mt = w, nt = i;            // e-tile = wave, d-tile = i
        f32x4 aR = zf, aI = zf;
        #pragma unroll
        for (int ks = 0; ks < 2; ++ks) {
            const f16x8 av = *(const f16x8*)&VWT[mt*16 + rl][ks*32 + kg*8];
            const f16x8 br = *(const f16x8*)&KTR[nt*16 + rl][ks*32 + kg*8];
            const f16x8 bi = *(const f16x8*)&KTI[nt*16 + rl][ks*32 + kg*8];
            aR = __builtin_amdgcn_mfma_f32_16x16x32_f16(av, br, aR, 0, 0, 0);
            aI = __builtin_amdgcn_mfma_f32_16x16x32_f16(av, bi, aI, 0, 0, 0);
        }
        const int d = nt*16 + rl;
        #pragma unroll
        for (int r = 0; r < 4; ++r) {
            const int e = mt*16 + kg*4 + r;
            dst[e*ND + d] = make_float2(aR[r], aI[r]);
        }
    }
}

// ---------------------------------------------------------------------------
// scan (transposed layout): kvB element idx = e*64+d.
// B_{c+1} = lambda_d^64 * B_c + KV_c; B_0 = last_conv (lc read transposed).
// ---------------------------------------------------------------------------
__global__ __launch_bounds__(256) void scan_kernel(
    float2* __restrict__ kvB,
    const float* __restrict__ lc_re, const float* __restrict__ lc_im,
    const float* __restrict__ ph_re, const float* __restrict__ ph_im,
    const float* __restrict__ ampl)
{
    const int gid = blockIdx.x * 256 + threadIdx.x;   // 65536
    const int bh = gid >> 12;
    const int idx = gid & 4095;
    const int h = bh & 7;
    const int d = idx & 63;                 // transposed: d is the fast index
    const int e = idx >> 6;

    const float th = atan2f(ph_im[h*ND + d], ph_re[h*ND + d]);
    const float la = -logf(1.0f + expf(-ampl[h]));
    const float ampC = expf(la * (float)CHUNK);
    float s, ct; sincosf(th * (float)CHUNK, &s, &ct);
    const float aCr = ampC * ct, aCi = ampC * s;

    float2* base = kvB + (size_t)bh * NC * (ND*ND) + idx;
    float2 t[NC];
    #pragma unroll
    for (int cc = 0; cc < NC; ++cc) t[cc] = base[(size_t)cc * (ND*ND)];

    float Sr = lc_re[h*ND*ND + d*ND + e];   // lc is [h][d][e]
    float Si = lc_im[h*ND*ND + d*ND + e];
    #pragma unroll
    for (int cc = 0; cc < NC; ++cc) {
        base[(size_t)cc * (ND*ND)] = make_float2(Sr, Si);
        const float nr = aCr*Sr - aCi*Si + t[cc].x;
        const float ni = aCr*Si + aCi*Sr + t[cc].y;
        Sr = nr; Si = ni;
    }
}

// ---------------------------------------------------------------------------
// chunk_out (MFMA): 512 blocks (bhc*2+half), 32 output rows each.
//  scores S = QhR.KhR^T + QhI.KhI^T  (8 mfma/wave)
//  SA = mask(S) -> fp16;  BT staged into Kh space (dead after scores)
//  O  = SA.V  (VT[e][jp])  + apw[jabs+1] * (QcR.BR + (-QcI).BI)
// ---------------------------------------------------------------------------
__global__ __launch_bounds__(256) void chunk_out_kernel(
    const float* __restrict__ q, const float* __restrict__ k, const float* __restrict__ v,
    const float2* __restrict__ Bst,
    const float* __restrict__ ph_re, const float* __restrict__ ph_im,
    const float* __restrict__ ampl, float* __restrict__ out)
{
    __shared__ __align__(16) _Float16 QhR[32][72], QhI[32][72];
    __shared__ __align__(16) _Float16 QcR[32][72], QcIn[32][72];
    __shared__ __align__(16) _Float16 KhR[64][72], KhI[64][72];   // -> BTR/BTI
    __shared__ __align__(16) _Float16 VT[64][72];
    __shared__ __align__(16) _Float16 SA[32][72];
    __shared__ float apw[80];

    const int half = blockIdx.x & 1;
    const int bhc = blockIdx.x >> 1;
    const int c  = bhc & (NC - 1);
    const int bh = bhc >> 4;
    const int b = bh >> 3, h = bh & 7;
    const int tid = threadIdx.x;
    const int lane = tid & 63, w = tid >> 6;
    const int rl = lane & 15, kg = lane >> 4;
    const int mt = w >> 1;                    // output row-tile of this wave

    const float la = -logf(1.0f + expf(-ampl[h]));
    if (tid < 72) apw[tid] = expf(la * (float)tid);
    const float th = atan2f(ph_im[h*ND + lane], ph_re[h*ND + lane]);
    float sth_, cth_; sincosf(th, &sth_, &cth_);

    // early B-state loads (lane-contiguous: idx = ii*256 + tid)
    float2 breg[16];
    const float2* Bb = Bst + (size_t)bhc * (ND*ND);
    #pragma unroll
    for (int ii = 0; ii < 16; ++ii) breg[ii] = Bb[ii*256 + tid];

    // stage Qh / Qc (rows of this half)
    #pragma unroll
    for (int jj = 0; jj < 8; ++jj) {
        const int row = w*8 + jj;
        const int jabs = half*32 + row;
        const size_t off = ((size_t)(b*L_SEQ + c*CHUNK + jabs)) * DIMSZ + h*ND + lane;
        const float qq = q[off];
        float s, cc; sincosf(th * (float)jabs, &s, &cc);
        const float qhr = qq * cc, qhi = qq * s;
        QhR[row][lane] = (_Float16)qhr;
        QhI[row][lane] = (_Float16)qhi;
        QcR[row][lane]  = (_Float16)(qhr*cth_ - qhi*sth_);
        QcIn[row][lane] = (_Float16)(-(qhr*sth_ + qhi*cth_));
    }
    // stage Kh (full 64 rows), V transposed
    #pragma unroll
    for (int jj = 0; jj < 16; ++jj) {
        const int j = w*16 + jj;
        const size_t off = ((size_t)(b*L_SEQ + c*CHUNK + j)) * DIMSZ + h*ND + lane;
        const float kk = k[off], vv = v[off];
        float s, cc; sincosf(th * (float)j, &s, &cc);
        KhR[j][lane] = (_Float16)(kk * cc);
        KhI[j][lane] = (_Float16)(kk * s);
        VT[lane][j]  = (_Float16)vv;
    }
    __syncthreads();

    // ---- scores ----
    const f32x4 zf = {0.f, 0.f, 0.f, 0.f};
    f32x4 sacc[2] = {zf, zf};
    #pragma unroll
    for (int t = 0; t < 2; ++t) {
        const int nt = (w & 1)*2 + t;
        #pragma unroll
        for (int ks = 0; ks < 2; ++ks) {
            const f16x8 aR = *(const f16x8*)&QhR[mt*16 + rl][ks*32 + kg*8];
            const f16x8 bR = *(const f16x8*)&KhR[nt*16 + rl][ks*32 + kg*8];
            sacc[t] = __builtin_amdgcn_mfma_f32_16x16x32_f16(aR, bR, sacc[t], 0, 0, 0);
            const f16x8 aI = *(const f16x8*)&QhI[mt*16 + rl][ks*32 + kg*8];
            const f16x8 bI = *(const f16x8*)&KhI[nt*16 + rl][ks*32 + kg*8];
            sacc[t] = __builtin_amdgcn_mfma_f32_16x16x32_f16(aI, bI, sacc[t], 0, 0, 0);
        }
    }
    __syncthreads();   // everyone done reading Kh

    // ---- SA = mask(scores) fp16;  BT -> Kh space ----
    #pragma unroll
    for (int t = 0; t < 2; ++t) {
        const int nt = (w & 1)*2 + t;
        #pragma unroll
        for (int r = 0; r < 4; ++r) {
            const int rowm = mt*16 + kg*4 + r;
            const int jabs = half*32 + rowm;
            const int jp = nt*16 + rl;
            const int delta = jabs - jp;
            const float val = (delta >= 0) ? sacc[t][r] * apw[delta] : 0.0f;
            SA[rowm][jp] = (_Float16)val;
        }
    }
    #pragma unroll
    for (int ii = 0; ii < 16; ++ii) {
        const int e = ii*4 + w;     // idx = ii*256 + tid -> e = ii*4 + w, d = lane
        KhR[e][lane] = (_Float16)breg[ii].x;
        KhI[e][lane] = (_Float16)breg[ii].y;
    }
    __syncthreads();

    // ---- PV + cross ----
    #pragma unroll
    for (int t = 0; t < 2; ++t) {
        const int nt = (w & 1)*2 + t;   // e-tile
        f32x4 accO = zf, accC = zf;
        #pragma unroll
        for (int ks = 0; ks < 2; ++ks) {
            const f16x8 aS = *(const f16x8*)&SA[mt*16 + rl][ks*32 + kg*8];
            const f16x8 bV = *(const f16x8*)&VT[nt*16 + rl][ks*32 + kg*8];
            accO = __builtin_amdgcn_mfma_f32_16x16x32_f16(aS, bV, accO, 0, 0, 0);
            const f16x8 aCR = *(const f16x8*)&QcR[mt*16 + rl][ks*32 + kg*8];
            const f16x8 bBR = *(const f16x8*)&KhR[nt*16 + rl][ks*32 + kg*8];
            accC = __builtin_amdgcn_mfma_f32_16x16x32_f16(aCR, bBR, accC, 0, 0, 0);
            const f16x8 aCI = *(const f16x8*)&QcIn[mt*16 + rl][ks*32 + kg*8];
            const f16x8 bBI = *(const f16x8*)&KhI[nt*16 + rl][ks*32 + kg*8];
            accC = __builtin_amdgcn_mfma_f32_16x16x32_f16(aCI, bBI, accC, 0, 0, 0);
        }
        const int e = nt*16 + rl;
        #pragma unroll
        for (int r = 0; r < 4; ++r) {
            const int rowm = mt*16 + kg*4 + r;
            const int jabs = half*32 + rowm;
            const float cs = apw[jabs + 1];
            out[((size_t)(b*L_SEQ + c*CHUNK + jabs)) * DIMSZ + h*ND + e] =
                accO[r] + cs * accC[r];
        }
    }
}

// ---------------------------------------------------------------------------
extern "C" void kernel_launch(void* const* d_in, const int* in_sizes, int n_in,
                              void* d_out, int out_size, void* d_ws, size_t ws_size,
                              hipStream_t stream)
{
    const float* x     = (const float*)d_in[0];
    const float* wq_w  = (const float*)d_in[1];
    const float* wq_b  = (const float*)d_in[2];
    const float* wk_w  = (const float*)d_in[3];
    const float* wk_b  = (const float*)d_in[4];
    const float* wv_w  = (const float*)d_in[5];
    const float* wv_b  = (const float*)d_in[6];
    const float* ph_re = (const float*)d_in[7];
    const float* ph_im = (const float*)d_in[8];
    const float* ampl  = (const float*)d_in[9];
    const float* lc_re = (const float*)d_in[10];
    const float* lc_im = (const float*)d_in[11];
    float* out = (float*)d_out;

    char* wsb = (char*)d_ws;
    const size_t MB = 1024 * 1024;
    float* q    = (float*)(wsb + 0);            // 4 MB
    float* k    = (float*)(wsb + 4 * MB);       // 4 MB
    float* v    = (float*)(wsb + 8 * MB);       // 4 MB
    float2* kvB = (float2*)(wsb + 12 * MB);     // 8 MB  (TRANSPOSED [e][d])
    unsigned short* Apk = (unsigned short*)(wsb + 20 * MB);  // 2 MB
    unsigned short* Bpk = (unsigned short*)(wsb + 23 * MB);  // 1.5 MB

    pack_kernel<<<1792, 256, 0, stream>>>(x, wq_w, wk_w, wv_w, Apk, Bpk);
    gemm_kernel<<<dim3(MTOT / BM, NTOT / BN), 256, 0, stream>>>(
        Apk, Bpk, wq_b, wk_b, wv_b, q, k, v);
    chunk_kv_kernel<<<BHTOT * NC, 256, 0, stream>>>(k, v, ph_re, ph_im, ampl, kvB);
    scan_kernel<<<256, 256, 0, stream>>>(kvB, lc_re, lc_im, ph_re, ph_im, ampl);
    chunk_out_kernel<<<BHTOT * NC * 2, 256, 0, stream>>>(
        q, k, v, kvB, ph_re, ph_im, ampl, out);
}